// Round 1
// baseline (23827.898 us; speedup 1.0000x reference)
//
#include <hip/hip_runtime.h>

// LSTMAutoEncoder: B=64, T=512, H=512, F=32.
// Only encoder layer 0 (final state) and decoder layer 0 feed the output:
//   out[:, t, :] = h_dec0_before_step(511 - t) @ W_out^T + b_out
// -> 1024 sequential LSTM cell steps, batch-parallel in 4 independent pods.

#define BB   64
#define TT   512
#define HH   512
#define FF   32
#define KU   544              // H + F fused K
#define KP   548              // padded U row stride (floats)
#define GP   36               // padded transposed-weight row stride (floats)
#define PODS 4
#define BT   16               // batch rows per pod
#define GBLK 64               // blocks per pod
#define JT   8                // hidden indices per block
#define GT   32               // gate rows per block (JT * 4 types)
#define NTHR 256
#define NBLK (PODS * GBLK)
#define LDS_FLOATS (KU * GP + BT * KP + 8 * 512 + GT)
#define LDS_BYTES  (LDS_FLOATS * 4)

typedef float f4v __attribute__((ext_vector_type(4)));

__device__ __forceinline__ float sigmf(float x)    { return 1.f / (1.f + __expf(-x)); }
__device__ __forceinline__ float tanhfast(float x) { return 1.f - 2.f / (__expf(2.f * x) + 1.f); }

// Monotonic-counter pod barrier (64 blocks). All blocks resident (1 block/CU,
// grid=256<=256 CUs) so spinning is deadlock-free. Agent-scope atomics+fences
// give cross-XCD visibility of h/c written before arrival.
__device__ __forceinline__ void pod_barrier(unsigned* ctr, unsigned* gen) {
  __syncthreads();
  if (threadIdx.x == 0) {
    __threadfence();
    const unsigned target = ++(*gen) * (unsigned)GBLK;
    __hip_atomic_fetch_add(ctr, 1u, __ATOMIC_RELEASE, __HIP_MEMORY_SCOPE_AGENT);
    while (__hip_atomic_load(ctr, __ATOMIC_ACQUIRE, __HIP_MEMORY_SCOPE_AGENT) < target)
      __builtin_amdgcn_s_sleep(1);
    __threadfence();
  }
  __syncthreads();
}

// Load this block's 32 gate rows (i,f,g,o for 8 hidden indices) into LDS,
// K-major transposed: WlT[k*GP + r] = W[gate_row(r)][k].  k<512 -> Whh, else Wih.
__device__ void load_wb(const float* __restrict__ Wih, const float* __restrict__ Whh,
                        const float* __restrict__ bih, const float* __restrict__ bhh,
                        float* WlT, float* Bl, int j0)
{
  const int tid = threadIdx.x;
  for (int idx = tid; idx < GT * (KU / 4); idx += NTHR) {
    const int r    = idx / (KU / 4);
    const int c4   = idx - r * (KU / 4);
    const int tau  = r >> 3, jl = r & 7;
    const int grow = tau * HH + j0 + jl;
    f4v v;
    if (c4 < HH / 4) v = *(const f4v*)&Whh[grow * HH + (c4 << 2)];
    else             v = *(const f4v*)&Wih[grow * FF + ((c4 - HH / 4) << 2)];
    const int k = c4 << 2;
    WlT[(k + 0) * GP + r] = v[0];
    WlT[(k + 1) * GP + r] = v[1];
    WlT[(k + 2) * GP + r] = v[2];
    WlT[(k + 3) * GP + r] = v[3];
  }
  if (tid < GT) {
    const int tau = tid >> 3, jl = tid & 7;
    const int grow = tau * HH + j0 + jl;
    Bl[tid] = bih[grow] + bhh[grow];
  }
}

__global__ void init_ws_kernel(float* hbuf, float* cbuf, unsigned* ctrs) {
  const int i = blockIdx.x * blockDim.x + threadIdx.x;
  if (i < BB * HH) { hbuf[i] = 0.f; cbuf[i] = 0.f; }
  if (i < PODS * 32) ctrs[i] = 0u;
}

__global__ void __launch_bounds__(NTHR, 1)
lstm_ae_kernel(const float* __restrict__ x,
               const float* __restrict__ eWih, const float* __restrict__ eWhh,
               const float* __restrict__ ebih, const float* __restrict__ ebhh,
               const float* __restrict__ dWih, const float* __restrict__ dWhh,
               const float* __restrict__ dbih, const float* __restrict__ dbhh,
               const float* __restrict__ Wo,  const float* __restrict__ bo,
               float* __restrict__ out, float* __restrict__ hbuf,
               float* __restrict__ cbuf, unsigned* __restrict__ ctrs)
{
  extern __shared__ float lds[];
  float* WlT = lds;                  // [KU][GP]  transposed weight slice
  float* U   = WlT + KU * GP;        // [BT][KP]  h | x_t
  float* Gr  = U + BT * KP;          // [8][512]  K-split partial gates / scratch
  float* Bl  = Gr + 8 * 512;         // [GT]      fused bias

  const int tid = threadIdx.x;
  const int blk = blockIdx.x;
  const int pod = blk & (PODS - 1);  // interleaved -> each pod sits on 2 XCDs
  const int gb  = blk >> 2;          // 0..63 within pod
  const int b0  = pod * BT;
  const int j0  = gb * JT;
  unsigned* ctr = ctrs + pod * 32;   // 128B-separated counters
  unsigned gen  = 0;

  // GEMM thread mapping: 8 K-groups x 32 threads; each thread a 4x4 tile.
  const int kg  = tid >> 5;
  const int t32 = tid & 31;
  const int bbr = (t32 & 3) << 2;    // batch row base (0,4,8,12)
  const int ggr = (t32 >> 2) << 2;   // gate row base  (0..28)
  const int k0  = kg * (KU / 8);     // 68-wide K slice

  load_wb(eWih, eWhh, ebih, ebhh, WlT, Bl, j0);
  __syncthreads();

  #pragma unroll 1
  for (int phase = 0; phase < 2; ++phase) {
    #pragma unroll 1
    for (int step = 0; step < TT; ++step) {
      const int t = phase ? (TT - 1 - step) : step;

      // Stage h (pod's 16 rows) and x[:, t, :] into LDS.
      #pragma unroll
      for (int rep = 0; rep < (BT * (HH / 4)) / NTHR; ++rep) {
        const int idx = rep * NTHR + tid;
        const int b = idx >> 7, k4 = (idx & 127) << 2;
        *(f4v*)&U[b * KP + k4] = *(const f4v*)&hbuf[(b0 + b) * HH + k4];
      }
      if (tid < BT * (FF / 4)) {
        const int b = tid >> 3, k4 = (tid & 7) << 2;
        *(f4v*)&U[b * KP + HH + k4] = *(const f4v*)&x[((b0 + b) * TT + t) * FF + k4];
      }
      __syncthreads();

      // Decoder: emit out[:, t, gb] from h BEFORE the cell update (blocks gb<32).
      if (phase && gb < FF) {
        const int f  = gb;
        const int ob = tid >> 4, seg = tid & 15;
        const float* wrow = Wo + f * HH + seg * 32;
        const float* urow = U + ob * KP + seg * 32;
        float p = 0.f;
        #pragma unroll
        for (int k = 0; k < 32; k += 4) {
          const f4v wv = *(const f4v*)(wrow + k);
          const f4v uv = *(const f4v*)(urow + k);
          p += uv[0] * wv[0] + uv[1] * wv[1] + uv[2] * wv[2] + uv[3] * wv[3];
        }
        Gr[tid] = p;
        __syncthreads();
        if (tid < BT) {
          float s = 0.f;
          #pragma unroll
          for (int q = 0; q < 16; ++q) s += Gr[(tid << 4) + q];
          out[((b0 + tid) * TT + t) * FF + f] = s + bo[f];
        }
        __syncthreads();  // Gr reused below
      }

      // gates[b, r] partial GEMM over this thread's K slice.
      float acc[4][4];
      #pragma unroll
      for (int i = 0; i < 4; ++i)
        #pragma unroll
        for (int j = 0; j < 4; ++j) acc[i][j] = 0.f;

      for (int kk = 0; kk < KU / 8; kk += 4) {
        const int k = k0 + kk;
        const f4v u0 = *(const f4v*)&U[(bbr + 0) * KP + k];
        const f4v u1 = *(const f4v*)&U[(bbr + 1) * KP + k];
        const f4v u2 = *(const f4v*)&U[(bbr + 2) * KP + k];
        const f4v u3 = *(const f4v*)&U[(bbr + 3) * KP + k];
        #pragma unroll
        for (int c = 0; c < 4; ++c) {
          const f4v w = *(const f4v*)&WlT[(k + c) * GP + ggr];
          acc[0][0] += u0[c] * w[0]; acc[0][1] += u0[c] * w[1];
          acc[0][2] += u0[c] * w[2]; acc[0][3] += u0[c] * w[3];
          acc[1][0] += u1[c] * w[0]; acc[1][1] += u1[c] * w[1];
          acc[1][2] += u1[c] * w[2]; acc[1][3] += u1[c] * w[3];
          acc[2][0] += u2[c] * w[0]; acc[2][1] += u2[c] * w[1];
          acc[2][2] += u2[c] * w[2]; acc[2][3] += u2[c] * w[3];
          acc[3][0] += u3[c] * w[0]; acc[3][1] += u3[c] * w[1];
          acc[3][2] += u3[c] * w[2]; acc[3][3] += u3[c] * w[3];
        }
      }
      #pragma unroll
      for (int i = 0; i < 4; ++i) {
        const f4v r = { acc[i][0], acc[i][1], acc[i][2], acc[i][3] };
        *(f4v*)&Gr[kg * 512 + (bbr + i) * 32 + ggr] = r;
      }
      __syncthreads();

      // Reduce K-split partials, activations, state update for (16 b x 8 j).
      if (tid < BT * JT) {
        const int b = tid >> 3, jl = tid & 7;
        float si = Bl[jl], sf = Bl[8 + jl], sg = Bl[16 + jl], so = Bl[24 + jl];
        #pragma unroll
        for (int q = 0; q < 8; ++q) {
          const float* g = Gr + q * 512 + b * 32;
          si += g[jl]; sf += g[8 + jl]; sg += g[16 + jl]; so += g[24 + jl];
        }
        const int hi = (b0 + b) * HH + j0 + jl;
        const float cold = cbuf[hi];
        const float c2 = sigmf(sf) * cold + sigmf(si) * tanhfast(sg);
        const float h2 = sigmf(so) * tanhfast(c2);
        cbuf[hi] = c2;
        hbuf[hi] = h2;
      }
      pod_barrier(ctr, &gen);
    }
    if (phase == 0) {  // encoder done: switch this block's LDS to decoder weights
      load_wb(dWih, dWhh, dbih, dbhh, WlT, Bl, j0);
      __syncthreads();
    }
  }
}

extern "C" void kernel_launch(void* const* d_in, const int* in_sizes, int n_in,
                              void* d_out, int out_size, void* d_ws, size_t ws_size,
                              hipStream_t stream) {
  const float* x    = (const float*)d_in[0];
  const float* eWih = (const float*)d_in[1];   // enc_Wih0 [2048,32]
  const float* eWhh = (const float*)d_in[2];   // enc_Whh0 [2048,512]
  const float* ebih = (const float*)d_in[3];
  const float* ebhh = (const float*)d_in[4];
  // d_in[5..8] enc layer 1: dead (only feeds dead decoder layer 1)
  const float* dWih = (const float*)d_in[9];   // dec_Wih0
  const float* dWhh = (const float*)d_in[10];  // dec_Whh0
  const float* dbih = (const float*)d_in[11];
  const float* dbhh = (const float*)d_in[12];
  // d_in[13..16] dec layer 1: dead (hB/cB never reach outs)
  const float* Wo   = (const float*)d_in[17];  // [32,512]
  const float* bo   = (const float*)d_in[18];  // [32]
  float* out = (float*)d_out;

  float*    hbuf = (float*)d_ws;               // [64][512]
  float*    cbuf = hbuf + BB * HH;             // [64][512]
  unsigned* ctrs = (unsigned*)(cbuf + BB * HH);

  hipFuncSetAttribute(reinterpret_cast<const void*>(lstm_ae_kernel),
                      hipFuncAttributeMaxDynamicSharedMemorySize, LDS_BYTES);

  init_ws_kernel<<<dim3((BB * HH + NTHR - 1) / NTHR), dim3(NTHR), 0, stream>>>(hbuf, cbuf, ctrs);
  lstm_ae_kernel<<<dim3(NBLK), dim3(NTHR), LDS_BYTES, stream>>>(
      x, eWih, eWhh, ebih, ebhh, dWih, dWhh, dbih, dbhh, Wo, bo,
      out, hbuf, cbuf, ctrs);
}

// Round 2
// 9298.209 us; speedup vs baseline: 2.5626x; 2.5626x over previous
//
#include <hip/hip_runtime.h>

// LSTMAutoEncoder: B=64, T=512, H=512, F=32.
// Only encoder layer 0 (final state) and decoder layer 0 feed the output:
//   out[:, t, :] = h_dec0_before_step(511 - t) @ W_out^T + b_out
// -> 1024 sequential LSTM cell steps, batch-parallel in 4 independent pods.
//
// Sync design (round 2): NO agent-scope fences anywhere in the loop (they
// lower to buffer_wbl2/buffer_inv L2 walks ~20us/step). h is exchanged via
// sc1 write-through stores + sc1 bypass loads (coherent at the LLC regardless
// of XCD placement); c lives in a register (never crosses blocks); h is
// double-buffered by step parity so one relaxed-counter barrier/step is safe.

#define BB   64
#define TT   512
#define HH   512
#define FF   32
#define KU   544              // H + F fused K
#define KP   548              // padded U row stride (floats)
#define GP   36               // padded transposed-weight row stride (floats)
#define PODS 4
#define BT   16               // batch rows per pod
#define GBLK 64               // blocks per pod
#define JT   8                // hidden indices per block
#define GT   32               // gate rows per block (JT * 4 types)
#define NTHR 256
#define NBLK (PODS * GBLK)
#define LDS_FLOATS (KU * GP + BT * KP + 8 * 512 + GT)
#define LDS_BYTES  (LDS_FLOATS * 4)

typedef float f4v __attribute__((ext_vector_type(4)));
typedef unsigned long long u64;

__device__ __forceinline__ float sigmf(float x)    { return 1.f / (1.f + __expf(-x)); }
__device__ __forceinline__ float tanhfast(float x) { return 1.f - 2.f / (__expf(2.f * x) + 1.f); }

// Load this block's 32 gate rows (i,f,g,o for 8 hidden indices) into LDS,
// K-major transposed: WlT[k*GP + r] = W[gate_row(r)][k].  k<512 -> Whh, else Wih.
__device__ void load_wb(const float* __restrict__ Wih, const float* __restrict__ Whh,
                        const float* __restrict__ bih, const float* __restrict__ bhh,
                        float* WlT, float* Bl, int j0)
{
  const int tid = threadIdx.x;
  for (int idx = tid; idx < GT * (KU / 4); idx += NTHR) {
    const int r    = idx / (KU / 4);
    const int c4   = idx - r * (KU / 4);
    const int tau  = r >> 3, jl = r & 7;
    const int grow = tau * HH + j0 + jl;
    f4v v;
    if (c4 < HH / 4) v = *(const f4v*)&Whh[grow * HH + (c4 << 2)];
    else             v = *(const f4v*)&Wih[grow * FF + ((c4 - HH / 4) << 2)];
    const int k = c4 << 2;
    WlT[(k + 0) * GP + r] = v[0];
    WlT[(k + 1) * GP + r] = v[1];
    WlT[(k + 2) * GP + r] = v[2];
    WlT[(k + 3) * GP + r] = v[3];
  }
  if (tid < GT) {
    const int tau = tid >> 3, jl = tid & 7;
    const int grow = tau * HH + j0 + jl;
    Bl[tid] = bih[grow] + bhh[grow];
  }
}

__global__ void init_ws_kernel(float* hbuf, unsigned* ctrs) {
  const int i = blockIdx.x * blockDim.x + threadIdx.x;
  if (i < 2 * BB * HH) hbuf[i] = 0.f;
  if (i < PODS * 32) ctrs[i] = 0u;
}

__global__ void __launch_bounds__(NTHR, 1)
lstm_ae_kernel(const float* __restrict__ x,
               const float* __restrict__ eWih, const float* __restrict__ eWhh,
               const float* __restrict__ ebih, const float* __restrict__ ebhh,
               const float* __restrict__ dWih, const float* __restrict__ dWhh,
               const float* __restrict__ dbih, const float* __restrict__ dbhh,
               const float* __restrict__ Wo,  const float* __restrict__ bo,
               float* __restrict__ out, float* __restrict__ hbuf,
               unsigned* __restrict__ ctrs)
{
  extern __shared__ float lds[];
  float* WlT = lds;                  // [KU][GP]  transposed weight slice
  float* U   = WlT + KU * GP;        // [BT][KP]  h | x_t
  float* Gr  = U + BT * KP;          // [8][512]  K-split partial gates / scratch
  float* Bl  = Gr + 8 * 512;         // [GT]      fused bias

  const int tid = threadIdx.x;
  const int blk = blockIdx.x;
  const int pod = blk & (PODS - 1);
  const int gb  = blk >> 2;          // 0..63 within pod
  const int b0  = pod * BT;
  const int j0  = gb * JT;
  unsigned* ctr = ctrs + pod * 32;   // 128B-separated counters
  unsigned gen  = 0;
  int par = 0;

  // GEMM thread mapping: 8 K-groups x 32 threads; each thread a 4x4 tile.
  const int kg  = tid >> 5;
  const int t32 = tid & 31;
  const int bbr = (t32 & 3) << 2;    // batch row base (0,4,8,12)
  const int ggr = (t32 >> 2) << 2;   // gate row base  (0..28)
  const int k0  = kg * (KU / 8);     // 68-wide K slice

  // Update-phase ownership (static across steps -> c stays in a register).
  const bool upd = tid < BT * JT;
  const int  ub  = tid >> 3, ujl = tid & 7;
  float c_reg = 0.f;

  load_wb(eWih, eWhh, ebih, ebhh, WlT, Bl, j0);
  __syncthreads();

  #pragma unroll 1
  for (int phase = 0; phase < 2; ++phase) {
    #pragma unroll 1
    for (int step = 0; step < TT; ++step) {
      const int t = phase ? (TT - 1 - step) : step;
      const float* hrd = hbuf + par * (BB * HH);
      float*       hwr = hbuf + (par ^ 1) * (BB * HH);

      // Stage h (pod's 16 rows) into LDS via sc1 bypass loads (LLC-coherent).
      #pragma unroll
      for (int rep = 0; rep < (BT * (HH / 2)) / NTHR; ++rep) {
        const int idx = rep * NTHR + tid;     // u64 index, 256 per row
        const int b = idx >> 8, k2 = idx & 255;
        const u64 v = __hip_atomic_load(
            (const u64*)(hrd + (b0 + b) * HH) + k2,
            __ATOMIC_RELAXED, __HIP_MEMORY_SCOPE_AGENT);
        float2 f; __builtin_memcpy(&f, &v, 8);
        *(float2*)&U[b * KP + (k2 << 1)] = f;
      }
      // Stage x[:, t, :] (read-only input -> ordinary cached loads).
      if (tid < BT * (FF / 4)) {
        const int b = tid >> 3, k4 = (tid & 7) << 2;
        *(f4v*)&U[b * KP + HH + k4] = *(const f4v*)&x[((b0 + b) * TT + t) * FF + k4];
      }
      __syncthreads();

      // Decoder: emit out[:, t, gb] from h BEFORE the cell update (blocks gb<32).
      if (phase && gb < FF) {
        const int f  = gb;
        const int ob = tid >> 4, seg = tid & 15;
        const float* wrow = Wo + f * HH + seg * 32;
        const float* urow = U + ob * KP + seg * 32;
        float p = 0.f;
        #pragma unroll
        for (int k = 0; k < 32; k += 4) {
          const f4v wv = *(const f4v*)(wrow + k);
          const f4v uv = *(const f4v*)(urow + k);
          p += uv[0] * wv[0] + uv[1] * wv[1] + uv[2] * wv[2] + uv[3] * wv[3];
        }
        Gr[tid] = p;
        __syncthreads();
        if (tid < BT) {
          float s = 0.f;
          #pragma unroll
          for (int q = 0; q < 16; ++q) s += Gr[(tid << 4) + q];
          out[((b0 + tid) * TT + t) * FF + f] = s + bo[f];
        }
        __syncthreads();  // Gr reused below
      }

      // gates[b, r] partial GEMM over this thread's K slice.
      float acc[4][4];
      #pragma unroll
      for (int i = 0; i < 4; ++i)
        #pragma unroll
        for (int j = 0; j < 4; ++j) acc[i][j] = 0.f;

      for (int kk = 0; kk < KU / 8; kk += 4) {
        const int k = k0 + kk;
        const f4v u0 = *(const f4v*)&U[(bbr + 0) * KP + k];
        const f4v u1 = *(const f4v*)&U[(bbr + 1) * KP + k];
        const f4v u2 = *(const f4v*)&U[(bbr + 2) * KP + k];
        const f4v u3 = *(const f4v*)&U[(bbr + 3) * KP + k];
        #pragma unroll
        for (int c = 0; c < 4; ++c) {
          const f4v w = *(const f4v*)&WlT[(k + c) * GP + ggr];
          acc[0][0] += u0[c] * w[0]; acc[0][1] += u0[c] * w[1];
          acc[0][2] += u0[c] * w[2]; acc[0][3] += u0[c] * w[3];
          acc[1][0] += u1[c] * w[0]; acc[1][1] += u1[c] * w[1];
          acc[1][2] += u1[c] * w[2]; acc[1][3] += u1[c] * w[3];
          acc[2][0] += u2[c] * w[0]; acc[2][1] += u2[c] * w[1];
          acc[2][2] += u2[c] * w[2]; acc[2][3] += u2[c] * w[3];
          acc[3][0] += u3[c] * w[0]; acc[3][1] += u3[c] * w[1];
          acc[3][2] += u3[c] * w[2]; acc[3][3] += u3[c] * w[3];
        }
      }
      #pragma unroll
      for (int i = 0; i < 4; ++i) {
        const f4v r = { acc[i][0], acc[i][1], acc[i][2], acc[i][3] };
        *(f4v*)&Gr[kg * 512 + (bbr + i) * 32 + ggr] = r;
      }
      __syncthreads();

      // Reduce K-split partials, activations, state update for (16 b x 8 j).
      if (upd) {
        float si = Bl[ujl], sf = Bl[8 + ujl], sg = Bl[16 + ujl], so = Bl[24 + ujl];
        #pragma unroll
        for (int q = 0; q < 8; ++q) {
          const float* g = Gr + q * 512 + ub * 32;
          si += g[ujl]; sf += g[8 + ujl]; sg += g[16 + ujl]; so += g[24 + ujl];
        }
        const float c2 = sigmf(sf) * c_reg + sigmf(si) * tanhfast(sg);
        const float h2 = sigmf(so) * tanhfast(c2);
        c_reg = c2;
        // sc1 write-through store: visible at the LLC once vmcnt drains
        // (the __syncthreads below drains vmcnt(0) in every wave).
        __hip_atomic_store(&hwr[(b0 + ub) * HH + j0 + ujl], h2,
                           __ATOMIC_RELAXED, __HIP_MEMORY_SCOPE_AGENT);
      }

      // Pod barrier: relaxed monotonic counter, no fences, no cache ops.
      // Each block's reads of hrd completed before its arrival, so the
      // parity flip + counter alone make the exchange race-free.
      __syncthreads();
      if (tid == 0) {
        ++gen;
        __hip_atomic_fetch_add(ctr, 1u, __ATOMIC_RELAXED, __HIP_MEMORY_SCOPE_AGENT);
        while (__hip_atomic_load(ctr, __ATOMIC_RELAXED, __HIP_MEMORY_SCOPE_AGENT)
               < gen * (unsigned)GBLK)
          __builtin_amdgcn_s_sleep(1);
      }
      __syncthreads();
      par ^= 1;
    }
    if (phase == 0) {  // encoder done: switch this block's LDS to decoder weights
      load_wb(dWih, dWhh, dbih, dbhh, WlT, Bl, j0);
      __syncthreads();
    }
  }
}

extern "C" void kernel_launch(void* const* d_in, const int* in_sizes, int n_in,
                              void* d_out, int out_size, void* d_ws, size_t ws_size,
                              hipStream_t stream) {
  const float* x    = (const float*)d_in[0];
  const float* eWih = (const float*)d_in[1];   // enc_Wih0 [2048,32]
  const float* eWhh = (const float*)d_in[2];   // enc_Whh0 [2048,512]
  const float* ebih = (const float*)d_in[3];
  const float* ebhh = (const float*)d_in[4];
  // d_in[5..8] enc layer 1: dead (only feeds dead decoder layer 1)
  const float* dWih = (const float*)d_in[9];   // dec_Wih0
  const float* dWhh = (const float*)d_in[10];  // dec_Whh0
  const float* dbih = (const float*)d_in[11];
  const float* dbhh = (const float*)d_in[12];
  // d_in[13..16] dec layer 1: dead (hB/cB never reach outs)
  const float* Wo   = (const float*)d_in[17];  // [32,512]
  const float* bo   = (const float*)d_in[18];  // [32]
  float* out = (float*)d_out;

  float*    hbuf = (float*)d_ws;               // [2][64][512] parity-buffered h
  unsigned* ctrs = (unsigned*)(hbuf + 2 * BB * HH);

  hipFuncSetAttribute(reinterpret_cast<const void*>(lstm_ae_kernel),
                      hipFuncAttributeMaxDynamicSharedMemorySize, LDS_BYTES);

  init_ws_kernel<<<dim3((2 * BB * HH + NTHR - 1) / NTHR), dim3(NTHR), 0, stream>>>(hbuf, ctrs);
  lstm_ae_kernel<<<dim3(NBLK), dim3(NTHR), LDS_BYTES, stream>>>(
      x, eWih, eWhh, ebih, ebhh, dWih, dWhh, dbih, dbhh, Wo, bo,
      out, hbuf, ctrs);
}